// Round 6
// baseline (359.312 us; speedup 1.0000x reference)
//
#include <hip/hip_runtime.h>
#include <math.h>

// Problem constants
#define BN   32768
#define DIM  256
#define KC   1024
#define BN_EPS 1e-5f

// Output layout (floats) in d_out
#define QX_SIZE   (BN * DIM)
#define LOSS0_OFF (QX_SIZE)
#define LOSS1_OFF (QX_SIZE + 1)
#define IDX_OFF   (QX_SIZE + 2)
#define PERP_OFF  (QX_SIZE + 2 + BN)

// Workspace layout (float offsets)
#define WS_SUM    0     // 256
#define WS_SUMSQ  256   // 256
#define WS_COUNT  512   // 1
#define WS_LOSS   513   // 1
#define WS_COUNTS 1024  // 1024
#define WS_MU     2048  // 256
#define WS_SCALE  2304  // 256
#define WS_NV     2560  // 1
#define WS_CNORM  3072  // 1024
#define WS_ET     8192                    // eT: KC*DIM floats (262144)
#define WS_BF     (WS_ET + KC * DIM)      // bf16 frag array, 524288 shorts
#define WS_REQ_FLOATS (WS_BF + 262144)

typedef short bf16x8 __attribute__((ext_vector_type(8)));
typedef float f32x4  __attribute__((ext_vector_type(4)));
typedef float fvec4  __attribute__((ext_vector_type(4)));

static __device__ inline unsigned short f2bf(float f) {
    unsigned int u = __float_as_uint(f);
    return (unsigned short)((u + 0x7FFFu + ((u >> 16) & 1u)) >> 16);
}
static __device__ inline fvec4 nt_ld4(const void* p) {
    return __builtin_nontemporal_load((const fvec4*)p);
}
static __device__ inline void nt_st(float* p, float v) {
    __builtin_nontemporal_store(v, p);
}

// ---------------------------------------------------------------- kernel 1
// Fused pre-pass. Blocks 0..127: masked stats (LDS-reduced atomics).
// Blocks 128..255: bf16 hi/lo B-fragment build. Blocks 256..511: e -> eT.
__global__ __launch_bounds__(256) void k_pre(const float* __restrict__ x,
                                             const int* __restrict__ mask,
                                             const float* __restrict__ e,
                                             short* __restrict__ bfr,
                                             float* __restrict__ eT,
                                             float* __restrict__ ws) {
    int t = threadIdx.x;
    int b = blockIdx.x;
    if (b < 128) {
        __shared__ float s4[4 * 256];
        __shared__ float q4[4 * 256];
        __shared__ float cntS[4];
        int c4 = t & 63;
        int rsub = t >> 6;
        float s0=0.f,s1=0.f,s2=0.f,s3=0.f, q0=0.f,q1=0.f,q2=0.f,q3=0.f, cnt=0.f;
        int rbase = b * 4 + rsub;
        for (int i = 0; i < 64; ++i) {
            int r = rbase + i * 512;
            float m = (float)mask[r];
            fvec4 v = nt_ld4(&x[(size_t)r * DIM + c4 * 4]);
            cnt += m;
            float m0 = m*v.x, m1 = m*v.y, m2 = m*v.z, m3 = m*v.w;
            s0 += m0; s1 += m1; s2 += m2; s3 += m3;
            q0 = fmaf(m0, v.x, q0); q1 = fmaf(m1, v.y, q1);
            q2 = fmaf(m2, v.z, q2); q3 = fmaf(m3, v.w, q3);
        }
        int f = c4 * 4;
        s4[rsub * 256 + f + 0] = s0; s4[rsub * 256 + f + 1] = s1;
        s4[rsub * 256 + f + 2] = s2; s4[rsub * 256 + f + 3] = s3;
        q4[rsub * 256 + f + 0] = q0; q4[rsub * 256 + f + 1] = q1;
        q4[rsub * 256 + f + 2] = q2; q4[rsub * 256 + f + 3] = q3;
        if (c4 == 0) cntS[rsub] = cnt;
        __syncthreads();
        float stot = s4[t] + s4[256 + t] + s4[512 + t] + s4[768 + t];
        float qtot = q4[t] + q4[256 + t] + q4[512 + t] + q4[768 + t];
        atomicAdd(&ws[WS_SUM + t], stot);
        atomicAdd(&ws[WS_SUMSQ + t], qtot);
        if (t == 0)
            atomicAdd(&ws[WS_COUNT], cntS[0] + cntS[1] + cntS[2] + cntS[3]);
    } else if (b < 256) {
        int g = (b - 128) * 256 + t;  // 0..32767
        int lane = g & 63;
        int kc = (g >> 6) & 7;
        int nt = g >> 9;              // 0..63
        int n = nt * 16 + (lane & 15);
        int k0 = kc * 32 + ((lane >> 4) & 3) * 8;
        bf16x8 hv, lv;
        #pragma unroll
        for (int j = 0; j < 8; ++j) {
            float v = e[(size_t)(k0 + j) * KC + n];
            unsigned short h = f2bf(v);
            float hf = __uint_as_float((unsigned)h << 16);
            hv[j] = (short)h;
            lv[j] = (short)f2bf(v - hf);
        }
        int base = (((nt * 8 + kc) * 2) * 64 + lane) * 8;
        *(bf16x8*)&bfr[base] = hv;
        *(bf16x8*)&bfr[base + 512] = lv;
    } else {
        __shared__ float tile[32][33];
        int tb = b - 256;
        int bk = (tb & 31) * 32;
        int bd = (tb >> 5) * 32;
        int lx = t & 31;
        int ly = t >> 5;
        #pragma unroll
        for (int i = 0; i < 4; ++i)
            tile[ly + i * 8][lx] = e[(size_t)(bd + ly + i * 8) * KC + bk + lx];
        __syncthreads();
        #pragma unroll
        for (int i = 0; i < 4; ++i)
            eT[(size_t)(bk + ly + i * 8) * DIM + bd + lx] = tile[lx][ly + i * 8];
    }
}

// ---------------------------------------------------------------- kernel 2
__global__ __launch_bounds__(256) void k_finalize(const float* __restrict__ e,
                                                  const float* __restrict__ gamma,
                                                  float* __restrict__ ws) {
    int t = threadIdx.x;
    int b = blockIdx.x;
    if (b == 0) {
        float cnt = ws[WS_COUNT];
        float nv = fmaxf(cnt, 1.f);
        float mu = ws[WS_SUM + t] / nv;
        float var = ws[WS_SUMSQ + t] / nv - mu * mu;
        var = fmaxf(var, 0.f);
        ws[WS_MU + t] = mu;
        ws[WS_SCALE + t] = rsqrtf(var + BN_EPS) * gamma[t];
        if (t == 0) ws[WS_NV] = nv;
    } else {
        int k = (b - 1) * 256 + t;
        float acc = 0.f;
        #pragma unroll 8
        for (int d = 0; d < DIM; ++d) {
            float v = e[(size_t)d * KC + k];
            acc = fmaf(v, v, acc);
        }
        ws[WS_CNORM + k] = acc;
    }
}

// ---------------------------------------------------------------- kernel 3
// MFMA main, R6: 128 rows/block (grid=256, 1 block/CU). A hi/lo fully LDS-
// resident (128 KB) -> barrier-free K loop; B register-double-buffered from
// L2 (per-block B traffic halved vs R5). 3-pass split-bf16, exact |e_k|^2.
#define RBM 128
struct RedT { float rv[RBM * 65]; int ri[RBM * 65]; };
__global__ __launch_bounds__(256, 1) void k_main_mfma(
        const float* __restrict__ x, const int* __restrict__ mask,
        const short* __restrict__ bfr, const float* __restrict__ eT,
        const float* __restrict__ beta, float* __restrict__ ws,
        float* __restrict__ out) {
    __shared__ union {
        short afrag[8 * 8 * 2 * 64 * 8];   // [kc][mt0..7][h][lane][8] = 128 KB
        RedT red;                           // 66.6 KB, reused post-GEMM
    } u;
    __shared__ float muS[DIM], scS[DIM], btS[DIM];
    __shared__ int   idxS[RBM];
    __shared__ float mskS[RBM];
    __shared__ float wred[4];

    const int tid = threadIdx.x;
    const int row0 = blockIdx.x * RBM;
    const int w = tid >> 6;
    const int lane = tid & 63;
    const int quad = lane >> 4;
    const int col0 = lane & 15;

    muS[tid] = ws[WS_MU + tid];
    scS[tid] = ws[WS_SCALE + tid];
    btS[tid] = beta[tid];
    __syncthreads();

    // ---- stage A-fragments: wave w stages mtiles 2w, 2w+1
    #pragma unroll
    for (int mi = 0; mi < 2; ++mi) {
        const int mt = w * 2 + mi;
        const int m = mt * 16 + col0;
        const int kq = quad * 8;
        const float* xr = x + (size_t)(row0 + m) * DIM;
        #pragma unroll
        for (int kc = 0; kc < 8; ++kc) {
            int k0 = kc * 32 + kq;
            fvec4 v0 = nt_ld4(xr + k0);
            fvec4 v1 = nt_ld4(xr + k0 + 4);
            float xv[8] = {v0.x, v0.y, v0.z, v0.w, v1.x, v1.y, v1.z, v1.w};
            bf16x8 hv, lv;
            #pragma unroll
            for (int j = 0; j < 8; ++j) {
                float xb = fmaf(xv[j] - muS[k0 + j], scS[k0 + j], btS[k0 + j]);
                unsigned short h = f2bf(xb);
                float hf = __uint_as_float((unsigned)h << 16);
                hv[j] = (short)h;
                lv[j] = (short)f2bf(xb - hf);
            }
            int base = (((kc * 8 + mt) * 2) * 64 + lane) * 8;
            *(bf16x8*)&u.afrag[base] = hv;
            *(bf16x8*)&u.afrag[base + 512] = lv;
        }
    }
    __syncthreads();

    // ---- GEMM: wave w covers codes [w*256, w*256+256), 4 ngroups of 64
    float minv[32];
    int   mini[32];
    #pragma unroll
    for (int i = 0; i < 32; ++i) { minv[i] = 3.4e38f; mini[i] = 0; }

    for (int ng = 0; ng < 4; ++ng) {
        f32x4 acc[8][4];
        #pragma unroll
        for (int mt = 0; mt < 8; ++mt)
            #pragma unroll
            for (int nt = 0; nt < 4; ++nt)
                acc[mt][nt] = (f32x4){0.f, 0.f, 0.f, 0.f};

        bf16x8 bh[2][4], bl[2][4];
        #pragma unroll
        for (int nt = 0; nt < 4; ++nt) {
            const short* bp = bfr +
                (size_t)((((w * 16 + ng * 4 + nt) * 8 + 0) * 2) * 64 + lane) * 8;
            bh[0][nt] = *(const bf16x8*)bp;
            bl[0][nt] = *(const bf16x8*)(bp + 512);
        }

        #pragma unroll
        for (int kc = 0; kc < 8; ++kc) {
            const int cur = kc & 1, nxt = cur ^ 1;
            if (kc < 7) {
                #pragma unroll
                for (int nt = 0; nt < 4; ++nt) {
                    const short* bp = bfr +
                        (size_t)((((w * 16 + ng * 4 + nt) * 8 + kc + 1) * 2) * 64 + lane) * 8;
                    bh[nxt][nt] = *(const bf16x8*)bp;
                    bl[nxt][nt] = *(const bf16x8*)(bp + 512);
                }
            }
            bf16x8 ah[8], al[8];
            #pragma unroll
            for (int mt = 0; mt < 8; ++mt) {
                int base = (((kc * 8 + mt) * 2) * 64 + lane) * 8;
                ah[mt] = *(const bf16x8*)&u.afrag[base];
                al[mt] = *(const bf16x8*)&u.afrag[base + 512];
            }
            // pass-major ordering: independent MFMAs back-to-back
            #pragma unroll
            for (int nt = 0; nt < 4; ++nt)
                #pragma unroll
                for (int mt = 0; mt < 8; ++mt)
                    acc[mt][nt] = __builtin_amdgcn_mfma_f32_16x16x32_bf16(
                        ah[mt], bh[cur][nt], acc[mt][nt], 0, 0, 0);
            #pragma unroll
            for (int nt = 0; nt < 4; ++nt)
                #pragma unroll
                for (int mt = 0; mt < 8; ++mt)
                    acc[mt][nt] = __builtin_amdgcn_mfma_f32_16x16x32_bf16(
                        ah[mt], bl[cur][nt], acc[mt][nt], 0, 0, 0);
            #pragma unroll
            for (int nt = 0; nt < 4; ++nt)
                #pragma unroll
                for (int mt = 0; mt < 8; ++mt)
                    acc[mt][nt] = __builtin_amdgcn_mfma_f32_16x16x32_bf16(
                        al[mt], bh[cur][nt], acc[mt][nt], 0, 0, 0);
        }
        // scores + running min (k ascending -> first-min tie semantics)
        #pragma unroll
        for (int nt = 0; nt < 4; ++nt) {
            int kcode = w * 256 + ng * 64 + nt * 16 + col0;
            float cn = ws[WS_CNORM + kcode];
            #pragma unroll
            for (int mt = 0; mt < 8; ++mt)
                #pragma unroll
                for (int r = 0; r < 4; ++r) {
                    float s = fmaf(-2.f, acc[mt][nt][r], cn);
                    int slot = mt * 4 + r;
                    if (s < minv[slot]) { minv[slot] = s; mini[slot] = kcode; }
                }
        }
    }

    // ---- cross-wave argmin reduction (reuse A-frag LDS)
    __syncthreads();
    #pragma unroll
    for (int mt = 0; mt < 8; ++mt)
        #pragma unroll
        for (int r = 0; r < 4; ++r) {
            int row = mt * 16 + quad * 4 + r;
            int ent = w * 16 + col0;
            u.red.rv[row * 65 + ent] = minv[mt * 4 + r];
            u.red.ri[row * 65 + ent] = mini[mt * 4 + r];
        }
    __syncthreads();
    if (tid < RBM) {
        float bv = u.red.rv[tid * 65];
        int bi = u.red.ri[tid * 65];
        for (int t2 = 1; t2 < 64; ++t2) {
            float v = u.red.rv[tid * 65 + t2];
            int ii = u.red.ri[tid * 65 + t2];
            if (v < bv || (v == bv && ii < bi)) { bv = v; bi = ii; }
        }
        int m = mask[row0 + tid];
        idxS[tid] = bi;
        mskS[tid] = (float)m;
        out[IDX_OFF + row0 + tid] = m ? (float)bi : -1.0f;
        if (m) atomicAdd(&ws[WS_COUNTS + bi], 1.0f);
    }
    __syncthreads();

    // ---- epilogue: gather q (coalesced via eT), write out, loss partial
    float lacc = 0.f;
    float mu = muS[tid], sc = scS[tid], bt = btS[tid];
    for (int r = 0; r < RBM; ++r) {
        int idx = idxS[r];
        float m = mskS[r];
        float q = eT[(size_t)idx * DIM + tid];
        float v = __builtin_nontemporal_load(&x[(size_t)(row0 + r) * DIM + tid]);
        float xb = fmaf(v - mu, sc, bt);
        float diff = xb - q;
        lacc = fmaf(m * diff, diff, lacc);
        nt_st(&out[(size_t)(row0 + r) * DIM + tid], (m != 0.f) ? q : 0.f);
    }
    #pragma unroll
    for (int off = 32; off > 0; off >>= 1) lacc += __shfl_down(lacc, off, 64);
    if ((tid & 63) == 0) wred[tid >> 6] = lacc;
    __syncthreads();
    if (tid == 0)
        atomicAdd(&ws[WS_LOSS], wred[0] + wred[1] + wred[2] + wred[3]);
}

// ---------------------------------------------------------------- kernel 3f
// Fallback f32 path if workspace is too small (proven R2 kernel).
#define RB  32
#define CB  512
#define DBC 8
#define APAD 36
__global__ __launch_bounds__(256, 3) void k_main_f32(const float* __restrict__ x,
                                                     const int* __restrict__ mask,
                                                     const float* __restrict__ e,
                                                     const float* __restrict__ beta,
                                                     float* __restrict__ ws,
                                                     float* __restrict__ out) {
    __shared__ __align__(16) float As[DIM * APAD];
    __shared__ __align__(16) float Bs[DBC * CB];
    __shared__ int   idxs_sh[RB];
    __shared__ float msh[RB];
    __shared__ float wred[4];

    int tid = threadIdx.x;
    int row0 = blockIdx.x * RB;
    float mu = ws[WS_MU + tid];
    float sc = ws[WS_SCALE + tid];
    float bt = beta[tid];
    #pragma unroll 4
    for (int r = 0; r < RB; ++r) {
        float v = x[(size_t)(row0 + r) * DIM + tid];
        As[tid * APAD + r] = fmaf(v - mu, sc, bt);
    }
    int ti = tid >> 6;
    int tj = tid & 63;
    float minv[8];
    int   mini[8];
    #pragma unroll
    for (int i = 0; i < 8; ++i) { minv[i] = 3.4e38f; mini[i] = 0; }
    const float4* e4 = (const float4*)e;
    for (int kb = 0; kb < 2; ++kb) {
        int kbase = kb * CB;
        float acc[8][8];
        #pragma unroll
        for (int i = 0; i < 8; ++i)
            #pragma unroll
            for (int j = 0; j < 8; ++j) acc[i][j] = 0.f;
        for (int dc = 0; dc < DIM / DBC; ++dc) {
            int d0 = dc * DBC;
            __syncthreads();
            #pragma unroll
            for (int p = 0; p < 4; ++p) {
                int lin = p * 256 + tid;
                int dd = lin >> 7;
                int kq = lin & 127;
                *(float4*)&Bs[dd * CB + kq * 4] =
                    e4[(size_t)(d0 + dd) * (KC / 4) + (kbase >> 2) + kq];
            }
            __syncthreads();
            #pragma unroll
            for (int dd = 0; dd < DBC; ++dd) {
                int dg = d0 + dd;
                float4 a0 = *(const float4*)&As[dg * APAD + ti * 8];
                float4 a1 = *(const float4*)&As[dg * APAD + ti * 8 + 4];
                float4 b0 = *(const float4*)&Bs[dd * CB + tj * 4];
                float4 b1 = *(const float4*)&Bs[dd * CB + 256 + tj * 4];
                float a[8] = {a0.x, a0.y, a0.z, a0.w, a1.x, a1.y, a1.z, a1.w};
                float b[8] = {b0.x, b0.y, b0.z, b0.w, b1.x, b1.y, b1.z, b1.w};
                #pragma unroll
                for (int i = 0; i < 8; ++i)
                    #pragma unroll
                    for (int j = 0; j < 8; ++j)
                        acc[i][j] = fmaf(a[i], b[j], acc[i][j]);
            }
        }
        #pragma unroll
        for (int g = 0; g < 2; ++g)
            #pragma unroll
            for (int jj = 0; jj < 4; ++jj) {
                int j = g * 4 + jj;
                int k = kbase + g * 256 + tj * 4 + jj;
                float c = ws[WS_CNORM + k];
                #pragma unroll
                for (int i = 0; i < 8; ++i) {
                    float s = fmaf(-2.f, acc[i][j], c);
                    if (s < minv[i]) { minv[i] = s; mini[i] = k; }
                }
            }
    }
    __syncthreads();
    float* redv = Bs;
    int*   redi = (int*)(Bs + RB * 64);
    #pragma unroll
    for (int i = 0; i < 8; ++i) {
        int r = ti * 8 + i;
        redv[r * 64 + tj] = minv[i];
        redi[r * 64 + tj] = mini[i];
    }
    __syncthreads();
    if (tid < RB) {
        int r = tid;
        float bv = redv[r * 64];
        int bi = redi[r * 64];
        for (int t2 = 1; t2 < 64; ++t2) {
            float v = redv[r * 64 + t2];
            int ii = redi[r * 64 + t2];
            if (v < bv || (v == bv && ii < bi)) { bv = v; bi = ii; }
        }
        int m = mask[row0 + r];
        idxs_sh[r] = bi;
        msh[r] = (float)m;
        out[IDX_OFF + row0 + r] = m ? (float)bi : -1.0f;
        if (m) atomicAdd(&ws[WS_COUNTS + bi], 1.0f);
    }
    __syncthreads();
    float lacc = 0.f;
    #pragma unroll 4
    for (int r = 0; r < RB; ++r) {
        int idx = idxs_sh[r];
        float m = msh[r];
        float q = e[(size_t)tid * KC + idx];
        float xb = As[tid * APAD + r];
        float diff = xb - q;
        lacc = fmaf(m * diff, diff, lacc);
        out[(size_t)(row0 + r) * DIM + tid] = (m != 0.f) ? q : 0.f;
    }
    #pragma unroll
    for (int off = 32; off > 0; off >>= 1) lacc += __shfl_down(lacc, off, 64);
    if ((tid & 63) == 0) wred[tid >> 6] = lacc;
    __syncthreads();
    if (tid == 0)
        atomicAdd(&ws[WS_LOSS], wred[0] + wred[1] + wred[2] + wred[3]);
}

// ---------------------------------------------------------------- kernel 4
__global__ __launch_bounds__(256) void k_final(const float* __restrict__ ws,
                                               float* __restrict__ out) {
    int t = threadIdx.x;
    __shared__ float wr[4];
    float nv = ws[WS_NV];
    float acc = 0.f;
    for (int j = t; j < KC; j += 256) {
        float p = ws[WS_COUNTS + j] / nv;
        acc = fmaf(p, logf(p + 1e-10f), acc);
    }
    #pragma unroll
    for (int off = 32; off > 0; off >>= 1) acc += __shfl_down(acc, off, 64);
    if ((t & 63) == 0) wr[t >> 6] = acc;
    __syncthreads();
    if (t == 0) {
        float ent = wr[0] + wr[1] + wr[2] + wr[3];
        float loss = ws[WS_LOSS] / (nv * (float)DIM);
        out[LOSS0_OFF] = loss;
        out[LOSS1_OFF] = loss;
        out[PERP_OFF] = expf(-ent);
    }
}

// ---------------------------------------------------------------- launch
extern "C" void kernel_launch(void* const* d_in, const int* in_sizes, int n_in,
                              void* d_out, int out_size, void* d_ws, size_t ws_size,
                              hipStream_t stream) {
    const float* x     = (const float*)d_in[0];
    const int*   amask = (const int*)d_in[1];
    const float* e     = (const float*)d_in[2];
    const float* gamma = (const float*)d_in[3];
    const float* beta  = (const float*)d_in[4];
    float* out = (float*)d_out;
    float* ws  = (float*)d_ws;

    (void)hipMemsetAsync(d_ws, 0, 8192, stream);

    if (ws_size >= (size_t)WS_REQ_FLOATS * sizeof(float)) {
        short* bfr = (short*)(ws + WS_BF);
        float* eT  = ws + WS_ET;
        k_pre<<<512, 256, 0, stream>>>(x, amask, e, bfr, eT, ws);
        k_finalize<<<5, 256, 0, stream>>>(e, gamma, ws);
        k_main_mfma<<<BN / RBM, 256, 0, stream>>>(x, amask, bfr, eT, beta, ws, out);
    } else {
        k_pre<<<128, 256, 0, stream>>>(x, amask, e, (short*)(ws + WS_MU),
                                       ws + WS_ET, ws); // stats blocks only
        k_finalize<<<5, 256, 0, stream>>>(e, gamma, ws);
        k_main_f32<<<BN / RB, 256, 0, stream>>>(x, amask, e, beta, ws, out);
    }
    k_final<<<1, 256, 0, stream>>>(ws, out);
}

// Round 7
// 324.939 us; speedup vs baseline: 1.1058x; 1.1058x over previous
//
#include <hip/hip_runtime.h>
#include <math.h>

// Problem constants
#define BN   32768
#define DIM  256
#define KC   1024
#define BN_EPS 1e-5f

// Output layout (floats) in d_out
#define QX_SIZE   (BN * DIM)
#define LOSS0_OFF (QX_SIZE)
#define LOSS1_OFF (QX_SIZE + 1)
#define IDX_OFF   (QX_SIZE + 2)
#define PERP_OFF  (QX_SIZE + 2 + BN)

// Workspace layout (float offsets)
#define WS_SUM    0     // 256
#define WS_SUMSQ  256   // 256
#define WS_COUNT  512   // 1
#define WS_LOSS   513   // 1
#define WS_COUNTS 1024  // 1024
#define WS_MU     2048  // 256
#define WS_SCALE  2304  // 256
#define WS_NV     2560  // 1
#define WS_CNORM  3072  // 1024
#define WS_ET     8192                    // eT: KC*DIM floats (262144)
#define WS_BF     (WS_ET + KC * DIM)      // bf16 frag array, 524288 shorts
#define WS_REQ_FLOATS (WS_BF + 262144)

typedef short bf16x8 __attribute__((ext_vector_type(8)));
typedef float f32x4  __attribute__((ext_vector_type(4)));
typedef float fvec4  __attribute__((ext_vector_type(4)));

static __device__ inline unsigned short f2bf(float f) {
    unsigned int u = __float_as_uint(f);
    return (unsigned short)((u + 0x7FFFu + ((u >> 16) & 1u)) >> 16);
}
static __device__ inline float bf2f(short s) {
    return __uint_as_float(((unsigned int)(unsigned short)s) << 16);
}
static __device__ inline fvec4 nt_ld4(const void* p) {
    return __builtin_nontemporal_load((const fvec4*)p);
}
static __device__ inline void nt_st(float* p, float v) {
    __builtin_nontemporal_store(v, p);
}

// ---------------------------------------------------------------- kernel 1
// Fused pre-pass. Blocks 0..127: masked stats (LDS-reduced atomics).
// Blocks 128..255: bf16 hi/lo B-fragment build. Blocks 256..511: e -> eT.
__global__ __launch_bounds__(256) void k_pre(const float* __restrict__ x,
                                             const int* __restrict__ mask,
                                             const float* __restrict__ e,
                                             short* __restrict__ bfr,
                                             float* __restrict__ eT,
                                             float* __restrict__ ws) {
    int t = threadIdx.x;
    int b = blockIdx.x;
    if (b < 128) {
        __shared__ float s4[4 * 256];
        __shared__ float q4[4 * 256];
        __shared__ float cntS[4];
        int c4 = t & 63;
        int rsub = t >> 6;
        float s0=0.f,s1=0.f,s2=0.f,s3=0.f, q0=0.f,q1=0.f,q2=0.f,q3=0.f, cnt=0.f;
        int rbase = b * 4 + rsub;
        for (int i = 0; i < 64; ++i) {
            int r = rbase + i * 512;
            float m = (float)mask[r];
            fvec4 v = nt_ld4(&x[(size_t)r * DIM + c4 * 4]);
            cnt += m;
            float m0 = m*v.x, m1 = m*v.y, m2 = m*v.z, m3 = m*v.w;
            s0 += m0; s1 += m1; s2 += m2; s3 += m3;
            q0 = fmaf(m0, v.x, q0); q1 = fmaf(m1, v.y, q1);
            q2 = fmaf(m2, v.z, q2); q3 = fmaf(m3, v.w, q3);
        }
        int f = c4 * 4;
        s4[rsub * 256 + f + 0] = s0; s4[rsub * 256 + f + 1] = s1;
        s4[rsub * 256 + f + 2] = s2; s4[rsub * 256 + f + 3] = s3;
        q4[rsub * 256 + f + 0] = q0; q4[rsub * 256 + f + 1] = q1;
        q4[rsub * 256 + f + 2] = q2; q4[rsub * 256 + f + 3] = q3;
        if (c4 == 0) cntS[rsub] = cnt;
        __syncthreads();
        float stot = s4[t] + s4[256 + t] + s4[512 + t] + s4[768 + t];
        float qtot = q4[t] + q4[256 + t] + q4[512 + t] + q4[768 + t];
        atomicAdd(&ws[WS_SUM + t], stot);
        atomicAdd(&ws[WS_SUMSQ + t], qtot);
        if (t == 0)
            atomicAdd(&ws[WS_COUNT], cntS[0] + cntS[1] + cntS[2] + cntS[3]);
    } else if (b < 256) {
        int g = (b - 128) * 256 + t;  // 0..32767
        int lane = g & 63;
        int kc = (g >> 6) & 7;
        int nt = g >> 9;              // 0..63
        int n = nt * 16 + (lane & 15);
        int k0 = kc * 32 + ((lane >> 4) & 3) * 8;
        bf16x8 hv, lv;
        #pragma unroll
        for (int j = 0; j < 8; ++j) {
            float v = e[(size_t)(k0 + j) * KC + n];
            unsigned short h = f2bf(v);
            float hf = __uint_as_float((unsigned)h << 16);
            hv[j] = (short)h;
            lv[j] = (short)f2bf(v - hf);
        }
        int base = (((nt * 8 + kc) * 2) * 64 + lane) * 8;
        *(bf16x8*)&bfr[base] = hv;
        *(bf16x8*)&bfr[base + 512] = lv;
    } else {
        __shared__ float tile[32][33];
        int tb = b - 256;
        int bk = (tb & 31) * 32;
        int bd = (tb >> 5) * 32;
        int lx = t & 31;
        int ly = t >> 5;
        #pragma unroll
        for (int i = 0; i < 4; ++i)
            tile[ly + i * 8][lx] = e[(size_t)(bd + ly + i * 8) * KC + bk + lx];
        __syncthreads();
        #pragma unroll
        for (int i = 0; i < 4; ++i)
            eT[(size_t)(bk + ly + i * 8) * DIM + bd + lx] = tile[lx][ly + i * 8];
    }
}

// ---------------------------------------------------------------- kernel 2
__global__ __launch_bounds__(256) void k_finalize(const float* __restrict__ e,
                                                  const float* __restrict__ gamma,
                                                  float* __restrict__ ws) {
    int t = threadIdx.x;
    int b = blockIdx.x;
    if (b == 0) {
        float cnt = ws[WS_COUNT];
        float nv = fmaxf(cnt, 1.f);
        float mu = ws[WS_SUM + t] / nv;
        float var = ws[WS_SUMSQ + t] / nv - mu * mu;
        var = fmaxf(var, 0.f);
        ws[WS_MU + t] = mu;
        ws[WS_SCALE + t] = rsqrtf(var + BN_EPS) * gamma[t];
        if (t == 0) ws[WS_NV] = nv;
    } else {
        int k = (b - 1) * 256 + t;
        float acc = 0.f;
        #pragma unroll 8
        for (int d = 0; d < DIM; ++d) {
            float v = e[(size_t)d * KC + k];
            acc = fmaf(v, v, acc);
        }
        ws[WS_CNORM + k] = acc;
    }
}

// ---------------------------------------------------------------- kernel 3
// MFMA main, R7: RB=64 (R5 shape, no spill), epilogue reconstructs xb from
// LDS A-fragments (no x re-read), shuffle-based argmin reduce (2 KB LDS).
__global__ __launch_bounds__(256, 2) void k_main_mfma(
        const float* __restrict__ x, const int* __restrict__ mask,
        const short* __restrict__ bfr, const float* __restrict__ eT,
        const float* __restrict__ beta, float* __restrict__ ws,
        float* __restrict__ out) {
    __shared__ short afrag[8 * 4 * 2 * 64 * 8];   // [kc][mt][h][lane][8] 64 KB
    __shared__ float muS[DIM], scS[DIM], btS[DIM];
    __shared__ float redv[64 * 4];
    __shared__ int   redi[64 * 4];
    __shared__ int   idxS[64];
    __shared__ float mskS[64];
    __shared__ float wred[4];

    const int tid = threadIdx.x;
    const int row0 = blockIdx.x * 64;
    const int w = tid >> 6;
    const int lane = tid & 63;
    const int quad = lane >> 4;
    const int col0 = lane & 15;

    muS[tid] = ws[WS_MU + tid];
    scS[tid] = ws[WS_SCALE + tid];
    btS[tid] = beta[tid];
    __syncthreads();

    // ---- stage A-fragments (normalize + hi/lo split), lane-frag order
    {
        const int mt = w;
        const int m = mt * 16 + col0;
        const int kq = quad * 8;
        const float* xr = x + (size_t)(row0 + m) * DIM;
        #pragma unroll
        for (int kc = 0; kc < 8; ++kc) {
            int k0 = kc * 32 + kq;
            fvec4 v0 = nt_ld4(xr + k0);
            fvec4 v1 = nt_ld4(xr + k0 + 4);
            float xv[8] = {v0.x, v0.y, v0.z, v0.w, v1.x, v1.y, v1.z, v1.w};
            bf16x8 hv, lv;
            #pragma unroll
            for (int j = 0; j < 8; ++j) {
                float xb = fmaf(xv[j] - muS[k0 + j], scS[k0 + j], btS[k0 + j]);
                unsigned short h = f2bf(xb);
                float hf = __uint_as_float((unsigned)h << 16);
                hv[j] = (short)h;
                lv[j] = (short)f2bf(xb - hf);
            }
            int base = (((kc * 4 + mt) * 2) * 64 + lane) * 8;
            *(bf16x8*)&afrag[base] = hv;
            *(bf16x8*)&afrag[base + 512] = lv;
        }
    }
    __syncthreads();

    // ---- GEMM: wave w covers codes [w*256, w*256+256), 4 ngroups of 64
    float minv[16];
    int   mini[16];
    #pragma unroll
    for (int i = 0; i < 16; ++i) { minv[i] = 3.4e38f; mini[i] = 0; }

    for (int ng = 0; ng < 4; ++ng) {
        f32x4 acc[4][4];
        #pragma unroll
        for (int mt = 0; mt < 4; ++mt)
            #pragma unroll
            for (int nt = 0; nt < 4; ++nt)
                acc[mt][nt] = (f32x4){0.f, 0.f, 0.f, 0.f};

        bf16x8 bh[2][4], bl[2][4];
        #pragma unroll
        for (int nt = 0; nt < 4; ++nt) {
            const short* bp = bfr +
                (size_t)((((w * 16 + ng * 4 + nt) * 8 + 0) * 2) * 64 + lane) * 8;
            bh[0][nt] = *(const bf16x8*)bp;
            bl[0][nt] = *(const bf16x8*)(bp + 512);
        }

        #pragma unroll
        for (int kc = 0; kc < 8; ++kc) {
            const int cur = kc & 1, nxt = cur ^ 1;
            if (kc < 7) {
                #pragma unroll
                for (int nt = 0; nt < 4; ++nt) {
                    const short* bp = bfr +
                        (size_t)((((w * 16 + ng * 4 + nt) * 8 + kc + 1) * 2) * 64 + lane) * 8;
                    bh[nxt][nt] = *(const bf16x8*)bp;
                    bl[nxt][nt] = *(const bf16x8*)(bp + 512);
                }
            }
            bf16x8 ah[4], al[4];
            #pragma unroll
            for (int mt = 0; mt < 4; ++mt) {
                int base = (((kc * 4 + mt) * 2) * 64 + lane) * 8;
                ah[mt] = *(const bf16x8*)&afrag[base];
                al[mt] = *(const bf16x8*)&afrag[base + 512];
            }
            #pragma unroll
            for (int nt = 0; nt < 4; ++nt)
                #pragma unroll
                for (int mt = 0; mt < 4; ++mt) {
                    acc[mt][nt] = __builtin_amdgcn_mfma_f32_16x16x32_bf16(
                        ah[mt], bh[cur][nt], acc[mt][nt], 0, 0, 0);
                    acc[mt][nt] = __builtin_amdgcn_mfma_f32_16x16x32_bf16(
                        ah[mt], bl[cur][nt], acc[mt][nt], 0, 0, 0);
                    acc[mt][nt] = __builtin_amdgcn_mfma_f32_16x16x32_bf16(
                        al[mt], bh[cur][nt], acc[mt][nt], 0, 0, 0);
                }
        }
        // scores + running min (k ascending -> first-min tie semantics)
        #pragma unroll
        for (int nt = 0; nt < 4; ++nt) {
            int kcode = w * 256 + ng * 64 + nt * 16 + col0;
            float cn = ws[WS_CNORM + kcode];
            #pragma unroll
            for (int mt = 0; mt < 4; ++mt)
                #pragma unroll
                for (int r = 0; r < 4; ++r) {
                    float s = fmaf(-2.f, acc[mt][nt][r], cn);
                    int slot = mt * 4 + r;
                    if (s < minv[slot]) { minv[slot] = s; mini[slot] = kcode; }
                }
        }
    }

    // ---- in-wave argmin reduce (16-lane butterfly over col0), then LDS
    #pragma unroll
    for (int s = 0; s < 16; ++s) {
        float v = minv[s];
        int   ii = mini[s];
        #pragma unroll
        for (int m2 = 1; m2 < 16; m2 <<= 1) {
            float v2 = __shfl_xor(v, m2, 64);
            int   i2 = __shfl_xor(ii, m2, 64);
            if (v2 < v || (v2 == v && i2 < ii)) { v = v2; ii = i2; }
        }
        int row = (s >> 2) * 16 + quad * 4 + (s & 3);
        if (col0 == 0) { redv[row * 4 + w] = v; redi[row * 4 + w] = ii; }
    }
    __syncthreads();
    if (tid < 64) {
        float bv = redv[tid * 4];
        int bi = redi[tid * 4];
        #pragma unroll
        for (int t2 = 1; t2 < 4; ++t2) {
            float v = redv[tid * 4 + t2];
            int ii = redi[tid * 4 + t2];
            if (v < bv || (v == bv && ii < bi)) { bv = v; bi = ii; }
        }
        int m = mask[row0 + tid];
        idxS[tid] = bi;
        mskS[tid] = (float)m;
        out[IDX_OFF + row0 + tid] = m ? (float)bi : -1.0f;
        if (m) atomicAdd(&ws[WS_COUNTS + bi], 1.0f);
    }
    __syncthreads();

    // ---- epilogue: gather q (L2-resident eT), xb rebuilt from LDS A-frags
    float lacc = 0.f;
    const int ekc = tid >> 5;          // which kc chunk
    const int equad = (tid >> 3) & 3;  // quad within chunk
    const int ej = tid & 7;            // element within frag
    for (int r = 0; r < 64; ++r) {
        int idx = idxS[r];
        float m = mskS[r];
        float q = eT[(size_t)idx * DIM + tid];
        int off = (((ekc * 4 + (r >> 4)) * 2) * 64 + equad * 16 + (r & 15)) * 8 + ej;
        float xb = bf2f(afrag[off]) + bf2f(afrag[off + 512]);
        float diff = xb - q;
        lacc = fmaf(m * diff, diff, lacc);
        nt_st(&out[(size_t)(row0 + r) * DIM + tid], (m != 0.f) ? q : 0.f);
    }
    #pragma unroll
    for (int off = 32; off > 0; off >>= 1) lacc += __shfl_down(lacc, off, 64);
    if ((tid & 63) == 0) wred[tid >> 6] = lacc;
    __syncthreads();
    if (tid == 0)
        atomicAdd(&ws[WS_LOSS], wred[0] + wred[1] + wred[2] + wred[3]);
}

// ---------------------------------------------------------------- kernel 3f
// Fallback f32 path if workspace is too small (proven R2 kernel).
#define RB  32
#define CB  512
#define DBC 8
#define APAD 36
__global__ __launch_bounds__(256, 3) void k_main_f32(const float* __restrict__ x,
                                                     const int* __restrict__ mask,
                                                     const float* __restrict__ e,
                                                     const float* __restrict__ beta,
                                                     float* __restrict__ ws,
                                                     float* __restrict__ out) {
    __shared__ __align__(16) float As[DIM * APAD];
    __shared__ __align__(16) float Bs[DBC * CB];
    __shared__ int   idxs_sh[RB];
    __shared__ float msh[RB];
    __shared__ float wred[4];

    int tid = threadIdx.x;
    int row0 = blockIdx.x * RB;
    float mu = ws[WS_MU + tid];
    float sc = ws[WS_SCALE + tid];
    float bt = beta[tid];
    #pragma unroll 4
    for (int r = 0; r < RB; ++r) {
        float v = x[(size_t)(row0 + r) * DIM + tid];
        As[tid * APAD + r] = fmaf(v - mu, sc, bt);
    }
    int ti = tid >> 6;
    int tj = tid & 63;
    float minv[8];
    int   mini[8];
    #pragma unroll
    for (int i = 0; i < 8; ++i) { minv[i] = 3.4e38f; mini[i] = 0; }
    const float4* e4 = (const float4*)e;
    for (int kb = 0; kb < 2; ++kb) {
        int kbase = kb * CB;
        float acc[8][8];
        #pragma unroll
        for (int i = 0; i < 8; ++i)
            #pragma unroll
            for (int j = 0; j < 8; ++j) acc[i][j] = 0.f;
        for (int dc = 0; dc < DIM / DBC; ++dc) {
            int d0 = dc * DBC;
            __syncthreads();
            #pragma unroll
            for (int p = 0; p < 4; ++p) {
                int lin = p * 256 + tid;
                int dd = lin >> 7;
                int kq = lin & 127;
                *(float4*)&Bs[dd * CB + kq * 4] =
                    e4[(size_t)(d0 + dd) * (KC / 4) + (kbase >> 2) + kq];
            }
            __syncthreads();
            #pragma unroll
            for (int dd = 0; dd < DBC; ++dd) {
                int dg = d0 + dd;
                float4 a0 = *(const float4*)&As[dg * APAD + ti * 8];
                float4 a1 = *(const float4*)&As[dg * APAD + ti * 8 + 4];
                float4 b0 = *(const float4*)&Bs[dd * CB + tj * 4];
                float4 b1 = *(const float4*)&Bs[dd * CB + 256 + tj * 4];
                float a[8] = {a0.x, a0.y, a0.z, a0.w, a1.x, a1.y, a1.z, a1.w};
                float b[8] = {b0.x, b0.y, b0.z, b0.w, b1.x, b1.y, b1.z, b1.w};
                #pragma unroll
                for (int i = 0; i < 8; ++i)
                    #pragma unroll
                    for (int j = 0; j < 8; ++j)
                        acc[i][j] = fmaf(a[i], b[j], acc[i][j]);
            }
        }
        #pragma unroll
        for (int g = 0; g < 2; ++g)
            #pragma unroll
            for (int jj = 0; jj < 4; ++jj) {
                int j = g * 4 + jj;
                int k = kbase + g * 256 + tj * 4 + jj;
                float c = ws[WS_CNORM + k];
                #pragma unroll
                for (int i = 0; i < 8; ++i) {
                    float s = fmaf(-2.f, acc[i][j], c);
                    if (s < minv[i]) { minv[i] = s; mini[i] = k; }
                }
            }
    }
    __syncthreads();
    float* redv = Bs;
    int*   redi = (int*)(Bs + RB * 64);
    #pragma unroll
    for (int i = 0; i < 8; ++i) {
        int r = ti * 8 + i;
        redv[r * 64 + tj] = minv[i];
        redi[r * 64 + tj] = mini[i];
    }
    __syncthreads();
    if (tid < RB) {
        int r = tid;
        float bv = redv[r * 64];
        int bi = redi[r * 64];
        for (int t2 = 1; t2 < 64; ++t2) {
            float v = redv[r * 64 + t2];
            int ii = redi[r * 64 + t2];
            if (v < bv || (v == bv && ii < bi)) { bv = v; bi = ii; }
        }
        int m = mask[row0 + r];
        idxs_sh[r] = bi;
        msh[r] = (float)m;
        out[IDX_OFF + row0 + r] = m ? (float)bi : -1.0f;
        if (m) atomicAdd(&ws[WS_COUNTS + bi], 1.0f);
    }
    __syncthreads();
    float lacc = 0.f;
    #pragma unroll 4
    for (int r = 0; r < RB; ++r) {
        int idx = idxs_sh[r];
        float m = msh[r];
        float q = e[(size_t)tid * KC + idx];
        float xb = As[tid * APAD + r];
        float diff = xb - q;
        lacc = fmaf(m * diff, diff, lacc);
        out[(size_t)(row0 + r) * DIM + tid] = (m != 0.f) ? q : 0.f;
    }
    #pragma unroll
    for (int off = 32; off > 0; off >>= 1) lacc += __shfl_down(lacc, off, 64);
    if ((tid & 63) == 0) wred[tid >> 6] = lacc;
    __syncthreads();
    if (tid == 0)
        atomicAdd(&ws[WS_LOSS], wred[0] + wred[1] + wred[2] + wred[3]);
}

// ---------------------------------------------------------------- kernel 4
__global__ __launch_bounds__(256) void k_final(const float* __restrict__ ws,
                                               float* __restrict__ out) {
    int t = threadIdx.x;
    __shared__ float wr[4];
    float nv = ws[WS_NV];
    float acc = 0.f;
    for (int j = t; j < KC; j += 256) {
        float p = ws[WS_COUNTS + j] / nv;
        acc = fmaf(p, logf(p + 1e-10f), acc);
    }
    #pragma unroll
    for (int off = 32; off > 0; off >>= 1) acc += __shfl_down(acc, off, 64);
    if ((t & 63) == 0) wr[t >> 6] = acc;
    __syncthreads();
    if (t == 0) {
        float ent = wr[0] + wr[1] + wr[2] + wr[3];
        float loss = ws[WS_LOSS] / (nv * (float)DIM);
        out[LOSS0_OFF] = loss;
        out[LOSS1_OFF] = loss;
        out[PERP_OFF] = expf(-ent);
    }
}

// ---------------------------------------------------------------- launch
extern "C" void kernel_launch(void* const* d_in, const int* in_sizes, int n_in,
                              void* d_out, int out_size, void* d_ws, size_t ws_size,
                              hipStream_t stream) {
    const float* x     = (const float*)d_in[0];
    const int*   amask = (const int*)d_in[1];
    const float* e     = (const float*)d_in[2];
    const float* gamma = (const float*)d_in[3];
    const float* beta  = (const float*)d_in[4];
    float* out = (float*)d_out;
    float* ws  = (float*)d_ws;

    (void)hipMemsetAsync(d_ws, 0, 8192, stream);

    if (ws_size >= (size_t)WS_REQ_FLOATS * sizeof(float)) {
        short* bfr = (short*)(ws + WS_BF);
        float* eT  = ws + WS_ET;
        k_pre<<<512, 256, 0, stream>>>(x, amask, e, bfr, eT, ws);
        k_finalize<<<5, 256, 0, stream>>>(e, gamma, ws);
        k_main_mfma<<<BN / 64, 256, 0, stream>>>(x, amask, bfr, eT, beta, ws, out);
    } else {
        k_pre<<<128, 256, 0, stream>>>(x, amask, e, (short*)(ws + WS_MU),
                                       ws + WS_ET, ws); // stats blocks only
        k_finalize<<<5, 256, 0, stream>>>(e, gamma, ws);
        k_main_f32<<<BN / RB, 256, 0, stream>>>(x, amask, e, beta, ws, out);
    }
    k_final<<<1, 256, 0, stream>>>(ws, out);
}